// Round 6
// baseline (50.657 us; speedup 1.0000x reference)
//
#include <hip/hip_runtime.h>
#include <hip/hip_bf16.h>
#include <math.h>

#define NUM_POS 17
#define SEQ 8192
#define BATCH 64
#define H1 128
#define H2 64
#define TILE_F 592  // floats per 32-row tile region (578 used + pad)

typedef __attribute__((ext_vector_type(8)))  short        s16x8;
typedef __attribute__((ext_vector_type(16))) float        f32x16;
typedef __attribute__((ext_vector_type(4)))  unsigned int u32x4;
typedef __attribute__((ext_vector_type(4)))  float        f32x4;

static __device__ __forceinline__ unsigned pkbf(float a, float b) {
    unsigned short ua = __builtin_bit_cast(unsigned short, __float2bfloat16(a));
    unsigned short ub = __builtin_bit_cast(unsigned short, __float2bfloat16(b));
    return (unsigned)ua | ((unsigned)ub << 16);
}

static __device__ __forceinline__ unsigned pkrelu(float a, float b) {
    return pkbf(fmaxf(a, 0.0f), fmaxf(b, 0.0f));
}

static __device__ __forceinline__ f32x16 zero16() {
    f32x16 z;
    #pragma unroll
    for (int i = 0; i < 16; ++i) z[i] = 0.0f;
    return z;
}

// prep:
//  W1tb[h][64]  = W1^T padded (col 51 = b1, cols 52..63 = 0)
//  W2tb[h2][144] = W2^T with k-dim permuted to match the C1' fragment order
//                  (col 128 = b2, cols 129..143 = 0)
//  A3[32][64]   = layer-3 "matrix": row 0 = W3 permuted to match the C2'
//                  fragment order, rows 1..31 = 0
__global__ void prep_kernel(const float* __restrict__ W1, const float* __restrict__ b1,
                            const float* __restrict__ W2, const float* __restrict__ b2,
                            const float* __restrict__ W3,
                            __hip_bfloat16* __restrict__ W1tb,
                            __hip_bfloat16* __restrict__ W2tb,
                            __hip_bfloat16* __restrict__ A3) {
    int i = blockIdx.x * 256 + threadIdx.x;
    if (i < H1 * 64) {
        int h = i >> 6, k = i & 63;
        float v = (k < 51) ? W1[k * H1 + h] : ((k == 51) ? b1[h] : 0.0f);
        W1tb[i] = __float2bfloat16(v);
    } else if (i < H1 * 64 + H2 * 144) {
        int j = i - H1 * 64;
        int h2 = j / 144, k = j - h2 * 144;
        float v;
        if (k < 128) {
            int kk = k >> 4, hb = (k >> 3) & 1, jj = k & 7;
            int hperm = (kk & 3) * 32 + 8 * (((kk >> 2) << 1) | (jj >> 2)) + (jj & 3) + 4 * hb;
            v = W2[hperm * H2 + h2];
        } else {
            v = (k == 128) ? b2[h2] : 0.0f;
        }
        W2tb[j] = __float2bfloat16(v);
    } else if (i < H1 * 64 + H2 * 144 + 32 * 64) {
        int j = i - (H1 * 64 + H2 * 144);
        int row = j >> 6, k = j & 63;
        float v = 0.0f;
        if (row == 0) {
            int kk = k >> 4, hb = (k >> 3) & 1, jj = k & 7;
            int f = kk & 1;
            int r = 8 * (kk >> 1) + jj;
            int h2 = 32 * f + (r & 3) + 8 * (r >> 2) + 4 * hb;
            v = W3[h2];
        }
        A3[j] = __float2bfloat16(v);
    }
}

// main: 1024 blocks x 4 waves; each wave computes 4 tiles of 32 output rows,
// with the next tile's window floats (LDS reads) prefetched into registers
// while the current tile's GEMM2/3 run.
__global__ __launch_bounds__(256, 2)
void lpe_mfma_kernel(const float* __restrict__ pos,
                     const __hip_bfloat16* __restrict__ W1tb,
                     const __hip_bfloat16* __restrict__ W2tb,
                     const __hip_bfloat16* __restrict__ A3,
                     const float* __restrict__ b3,
                     float* __restrict__ out) {
    __shared__ float sp[16 * TILE_F];  // 4 waves x 4 tiles = 37.9 KB

    const int tid  = threadIdx.x;
    const int wid  = tid >> 6;
    const int lane = tid & 63;
    const int ml   = lane & 31;
    const int hi   = lane >> 5;

    const int batch = blockIdx.x >> 4;  // 64 batches x 16 blocks
    const int blk   = blockIdx.x & 15;
    const int wrow0 = blk * 512 + wid * 128;

    // ---- stage all 4 tiles (float4, 16B-aligned bases), wave-private LDS ----
    #pragma unroll
    for (int t = 0; t < 4; ++t) {
        float* dst = sp + (wid * 4 + t) * TILE_F;
        const int srow0 = wrow0 + t * 32;
        const float* src = pos + ((size_t)batch * SEQ + srow0) * NUM_POS;
        const int lim = (SEQ - srow0) * NUM_POS;
        #pragma unroll
        for (int it = 0; it < 3; ++it) {
            int i = it * 64 + lane;
            if (i < 144) {
                f32x4 v;
                if (i * 4 + 4 <= lim) {
                    v = *reinterpret_cast<const f32x4*>(src + i * 4);
                } else {
                    v[0] = v[1] = v[2] = v[3] = 0.0f;
                }
                *reinterpret_cast<f32x4*>(dst + i * 4) = v;
            }
        }
        if (lane < 2) {
            int i = 576 + lane;
            dst[i] = (i < lim) ? src[i] : 0.0f;
        }
    }
    // wave-private LDS: same-wave ds_write -> ds_read ordering via lgkmcnt.

    const float b3v = b3[0];

    // constant bias B-fragment for GEMM2's k=128 step
    u32x4 b2cu; b2cu[0] = (hi == 0) ? 0x3f80u : 0u; b2cu[1] = 0u; b2cu[2] = 0u; b2cu[3] = 0u;
    const s16x8 B2C = __builtin_bit_cast(s16x8, b2cu);

    // per-lane window base within this wave's 4-tile LDS region.
    // F mapping: F[0..7]=off 0..7, F[8..15]=off 16..23, F[16..23]=off 32..39,
    // F[24..26]=off 48..50 (only used by hi=0; hi=1 reads are masked to 0).
    const float* fbase = sp + (wid * 4) * TILE_F + ml * NUM_POS + 8 * hi;

    float F[27];
    #pragma unroll
    for (int j = 0; j < 8; ++j) F[j]      = fbase[j];
    #pragma unroll
    for (int j = 0; j < 8; ++j) F[8 + j]  = fbase[16 + j];
    #pragma unroll
    for (int j = 0; j < 8; ++j) F[16 + j] = fbase[32 + j];
    #pragma unroll
    for (int j = 0; j < 3; ++j) F[24 + j] = fbase[48 + j];

    #pragma unroll 1
    for (int t = 0; t < 4; ++t) {
        const int srow0 = wrow0 + t * 32;

        // ---- pack current B1 fragments from prefetched F (F dies here) ----
        u32x4 B1u[4];
        #pragma unroll
        for (int kk = 0; kk < 3; ++kk) {
            u32x4 u;
            u[0] = pkbf(F[8 * kk + 0], F[8 * kk + 1]);
            u[1] = pkbf(F[8 * kk + 2], F[8 * kk + 3]);
            u[2] = pkbf(F[8 * kk + 4], F[8 * kk + 5]);
            u[3] = pkbf(F[8 * kk + 6], F[8 * kk + 7]);
            B1u[kk] = u;
        }
        {
            float x0 = hi ? 0.0f : F[24];
            float x1 = hi ? 0.0f : F[25];
            float x2 = hi ? 0.0f : F[26];
            float x3 = hi ? 0.0f : 1.0f;   // k=51 bias column
            u32x4 u;
            u[0] = pkbf(x0, x1); u[1] = pkbf(x2, x3); u[2] = 0u; u[3] = 0u;
            B1u[3] = u;
        }

        // ---- GEMM1' as two hf-pairs, relu-packed immediately (peak acc1 = 32) ----
        unsigned pk1[4][8];
        #pragma unroll
        for (int hp = 0; hp < 2; ++hp) {
            f32x16 a1a = zero16(), a1b = zero16();
            #pragma unroll
            for (int kk = 0; kk < 4; ++kk) {
                s16x8 aa = *reinterpret_cast<const s16x8*>(
                    W1tb + (((2 * hp + 0) * 32 + ml) * 64 + kk * 16 + hi * 8));
                a1a = __builtin_amdgcn_mfma_f32_32x32x16_bf16(
                    aa, __builtin_bit_cast(s16x8, B1u[kk]), a1a, 0, 0, 0);
                s16x8 ab = *reinterpret_cast<const s16x8*>(
                    W1tb + (((2 * hp + 1) * 32 + ml) * 64 + kk * 16 + hi * 8));
                a1b = __builtin_amdgcn_mfma_f32_32x32x16_bf16(
                    ab, __builtin_bit_cast(s16x8, B1u[kk]), a1b, 0, 0, 0);
            }
            #pragma unroll
            for (int j = 0; j < 8; ++j) {
                pk1[2 * hp + 0][j] = pkrelu(a1a[2 * j], a1a[2 * j + 1]);
                pk1[2 * hp + 1][j] = pkrelu(a1b[2 * j], a1b[2 * j + 1]);
            }
        }

        // ---- prefetch next tile's window floats (latency hides under GEMM2/3) ----
        if (t < 3) {
            const float* fb = fbase + (t + 1) * TILE_F;
            #pragma unroll
            for (int j = 0; j < 8; ++j) F[j]      = fb[j];
            #pragma unroll
            for (int j = 0; j < 8; ++j) F[8 + j]  = fb[16 + j];
            #pragma unroll
            for (int j = 0; j < 8; ++j) F[16 + j] = fb[32 + j];
            #pragma unroll
            for (int j = 0; j < 3; ++j) F[24 + j] = fb[48 + j];
        }

        // ---- GEMM2': B-frag for step kk = pk1[kk&3][4*(kk>>2) .. +3] ----
        f32x16 acc2[2];
        acc2[0] = zero16(); acc2[1] = zero16();
        #pragma unroll
        for (int kk = 0; kk < 8; ++kk) {
            const int hf = kk & 3;
            const int jb = (kk >> 2) * 4;
            u32x4 bu;
            bu[0] = pk1[hf][jb + 0];
            bu[1] = pk1[hf][jb + 1];
            bu[2] = pk1[hf][jb + 2];
            bu[3] = pk1[hf][jb + 3];
            const s16x8 bfrag = __builtin_bit_cast(s16x8, bu);
            #pragma unroll
            for (int f = 0; f < 2; ++f) {
                s16x8 a = *reinterpret_cast<const s16x8*>(
                    W2tb + ((f * 32 + ml) * 144 + kk * 16 + hi * 8));
                acc2[f] = __builtin_amdgcn_mfma_f32_32x32x16_bf16(a, bfrag, acc2[f], 0, 0, 0);
            }
        }
        #pragma unroll
        for (int f = 0; f < 2; ++f) {
            s16x8 a = *reinterpret_cast<const s16x8*>(
                W2tb + ((f * 32 + ml) * 144 + 128 + hi * 8));
            acc2[f] = __builtin_amdgcn_mfma_f32_32x32x16_bf16(a, B2C, acc2[f], 0, 0, 0);
        }

        // ---- relu+pack acc2 -> pk2 ----
        unsigned pk2[2][8];
        #pragma unroll
        for (int f = 0; f < 2; ++f)
            #pragma unroll
            for (int j = 0; j < 8; ++j)
                pk2[f][j] = pkrelu(acc2[f][2 * j], acc2[f][2 * j + 1]);

        // ---- GEMM3' as two independent 2-chains ----
        f32x16 acc3a = zero16(), acc3b = zero16();
        #pragma unroll
        for (int kk = 0; kk < 4; ++kk) {
            const int f  = kk & 1;
            const int jb = (kk >> 1) * 4;
            u32x4 bu;
            bu[0] = pk2[f][jb + 0];
            bu[1] = pk2[f][jb + 1];
            bu[2] = pk2[f][jb + 2];
            bu[3] = pk2[f][jb + 3];
            const s16x8 bfrag = __builtin_bit_cast(s16x8, bu);
            s16x8 a = *reinterpret_cast<const s16x8*>(
                A3 + (ml * 64 + kk * 16 + hi * 8));
            if (f == 0)
                acc3a = __builtin_amdgcn_mfma_f32_32x32x16_bf16(a, bfrag, acc3a, 0, 0, 0);
            else
                acc3b = __builtin_amdgcn_mfma_f32_32x32x16_bf16(a, bfrag, acc3b, 0, 0, 0);
        }

        // ---- epilogue: sigmoid + store (hi=0 lanes hold D row 0) ----
        if (hi == 0) {
            const int grow = srow0 + ml;
            if (grow < SEQ - 2) {
                float v = acc3a[0] + acc3b[0] + b3v;
                out[(size_t)batch * (SEQ - 2) + grow] = 1.0f / (1.0f + __expf(-v));
            }
        }
    }
}

extern "C" void kernel_launch(void* const* d_in, const int* in_sizes, int n_in,
                              void* d_out, int out_size, void* d_ws, size_t ws_size,
                              hipStream_t stream) {
    const float* pos = (const float*)d_in[0];
    const float* W1  = (const float*)d_in[1];
    const float* b1  = (const float*)d_in[2];
    const float* W2  = (const float*)d_in[3];
    const float* b2  = (const float*)d_in[4];
    const float* W3  = (const float*)d_in[5];
    const float* b3  = (const float*)d_in[6];
    float* out = (float*)d_out;

    __hip_bfloat16* W1tb = (__hip_bfloat16*)d_ws;                   // 8192  bf16 = 16 KB
    __hip_bfloat16* W2tb = (__hip_bfloat16*)((char*)d_ws + 16384);  // 9216  bf16 = 18 KB
    __hip_bfloat16* A3   = (__hip_bfloat16*)((char*)d_ws + 34816);  // 2048  bf16 =  4 KB

    const int prep_elems = H1 * 64 + H2 * 144 + 32 * 64;  // 19456
    prep_kernel<<<(prep_elems + 255) / 256, 256, 0, stream>>>(W1, b1, W2, b2, W3,
                                                              W1tb, W2tb, A3);

    // 64 batches x 16 blocks; each block = 4 waves x 4 tiles x 32 rows = 512 rows
    lpe_mfma_kernel<<<BATCH * 16, 256, 0, stream>>>(pos, W1tb, W2tb, A3, b3, out);
}

// Round 7
// 44.487 us; speedup vs baseline: 1.1387x; 1.1387x over previous
//
#include <hip/hip_runtime.h>
#include <hip/hip_bf16.h>
#include <math.h>

#define NUM_POS 17
#define SEQ 8192
#define BATCH 64
#define H1 128
#define H2 64
#define TILE_F 592   // floats per 32-row tile region (578 used + pad)
#define NFRAG 38     // 16 (GEMM1) + 18 (GEMM2 incl bias) + 4 (GEMM3)

typedef __attribute__((ext_vector_type(8)))  short        s16x8;
typedef __attribute__((ext_vector_type(16))) float        f32x16;
typedef __attribute__((ext_vector_type(4)))  unsigned int u32x4;
typedef __attribute__((ext_vector_type(4)))  float        f32x4;

static __device__ __forceinline__ unsigned pkbf(float a, float b) {
    unsigned short ua = __builtin_bit_cast(unsigned short, __float2bfloat16(a));
    unsigned short ub = __builtin_bit_cast(unsigned short, __float2bfloat16(b));
    return (unsigned)ua | ((unsigned)ub << 16);
}

static __device__ __forceinline__ unsigned pkrelu(float a, float b) {
    return pkbf(fmaxf(a, 0.0f), fmaxf(b, 0.0f));
}

static __device__ __forceinline__ f32x16 zero16() {
    f32x16 z;
    #pragma unroll
    for (int i = 0; i < 16; ++i) z[i] = 0.0f;
    return z;
}

// prep: write all 38 MFMA A-fragments frag-packed: Wp[frag][lane][8] bf16.
// Each frag is a contiguous 1KB block; lane (ml,hi) holds the 8 bf16 its
// MFMA A-operand slot needs. Wave-linear -> conflict-free LDS reads.
//  frags 0..15 : GEMM1, id = hf*4+kk.  A[h=hf*32+ml][k=kk*16+hi*8+j],
//                A = W1^T padded (col 51 = b1, cols 52..63 = 0)
//  frags 16..33: GEMM2, id = 16+kk9*2+f. kk9<8: A[h2=f*32+ml][k=kk9*16+hi*8+j]
//                of k-permuted W2^T; kk9==8: bias column (b2 at k-slot hi=0,j=0)
//  frags 34..37: GEMM3, id = 34+kk. Row 0 = W3 permuted to C2' order, rows 1..31 = 0
__global__ void prep_kernel(const float* __restrict__ W1, const float* __restrict__ b1,
                            const float* __restrict__ W2, const float* __restrict__ b2,
                            const float* __restrict__ W3,
                            __hip_bfloat16* __restrict__ Wp) {
    int idx = blockIdx.x * 256 + threadIdx.x;
    if (idx >= NFRAG * 512) return;
    int fragid = idx >> 9;
    int lane   = (idx >> 3) & 63;
    int j      = idx & 7;
    int ml = lane & 31, hi = lane >> 5;
    float v = 0.0f;
    if (fragid < 16) {
        int hf = fragid >> 2, kk = fragid & 3;
        int k = kk * 16 + hi * 8 + j;
        int h = hf * 32 + ml;
        v = (k < 51) ? W1[k * H1 + h] : ((k == 51) ? b1[h] : 0.0f);
    } else if (fragid < 34) {
        int g = fragid - 16;
        int kk9 = g >> 1, f = g & 1;
        int h2 = f * 32 + ml;
        if (kk9 < 8) {
            int k = kk9 * 16 + hi * 8 + j;
            int kk = k >> 4, hb = (k >> 3) & 1, jj = k & 7;
            int hperm = (kk & 3) * 32 + 8 * (((kk >> 2) << 1) | (jj >> 2)) + (jj & 3) + 4 * hb;
            v = W2[hperm * H2 + h2];
        } else {
            v = (hi == 0 && j == 0) ? b2[h2] : 0.0f;  // k==128 bias column
        }
    } else {
        int kk = fragid - 34;
        if (ml == 0) {
            int k = kk * 16 + hi * 8 + j;
            int kk2 = k >> 4, hb = (k >> 3) & 1, jj = k & 7;
            int f = kk2 & 1;
            int r = 8 * (kk2 >> 1) + jj;
            int h2 = 32 * f + (r & 3) + 8 * (r >> 2) + 4 * hb;
            v = W3[h2];
        }
    }
    Wp[idx] = __float2bfloat16(v);
}

// main: 2048 blocks x 4 waves; each wave computes 2 tiles of 32 output rows.
// Weights live in LDS (frag-packed, staged once per block).
__global__ __launch_bounds__(256, 2)
void lpe_mfma_kernel(const float* __restrict__ pos,
                     const __hip_bfloat16* __restrict__ Wp,
                     const float* __restrict__ b3,
                     float* __restrict__ out) {
    __shared__ __hip_bfloat16 wl[NFRAG * 512];  // 38912 B
    __shared__ float sp[8 * TILE_F];            // 18944 B  (total 57856 B)

    const int tid  = threadIdx.x;
    const int wid  = tid >> 6;
    const int lane = tid & 63;
    const int ml   = lane & 31;
    const int hi   = lane >> 5;

    const int batch = blockIdx.x >> 5;   // 64 batches x 32 blocks
    const int blk   = blockIdx.x & 31;
    const int wrow0 = blk * 256 + wid * 64;

    // ---- stage weights global -> LDS (coalesced 16B copies) ----
    {
        const u32x4* src = reinterpret_cast<const u32x4*>(Wp);
        u32x4* dst = reinterpret_cast<u32x4*>(wl);
        #pragma unroll
        for (int it = 0; it < 10; ++it) {
            int i = it * 256 + tid;
            if (i < NFRAG * 512 * 2 / 16) dst[i] = src[i];
        }
    }

    // ---- stage 2 window tiles per wave (float4, 16B-aligned bases) ----
    #pragma unroll
    for (int t = 0; t < 2; ++t) {
        float* dst = sp + (wid * 2 + t) * TILE_F;
        const int srow0 = wrow0 + t * 32;
        const float* src = pos + ((size_t)batch * SEQ + srow0) * NUM_POS;
        const int lim = (SEQ - srow0) * NUM_POS;
        #pragma unroll
        for (int it = 0; it < 3; ++it) {
            int i = it * 64 + lane;
            if (i < 144) {
                f32x4 v;
                if (i * 4 + 4 <= lim) {
                    v = *reinterpret_cast<const f32x4*>(src + i * 4);
                } else {
                    v[0] = v[1] = v[2] = v[3] = 0.0f;
                }
                *reinterpret_cast<f32x4*>(dst + i * 4) = v;
            }
        }
        if (lane < 2) {
            int i = 576 + lane;
            dst[i] = (i < lim) ? src[i] : 0.0f;
        }
    }
    __syncthreads();

    const float b3v = b3[0];

    // constant bias B-fragment for GEMM2's k=128 step
    u32x4 b2cu; b2cu[0] = (hi == 0) ? 0x3f80u : 0u; b2cu[1] = 0u; b2cu[2] = 0u; b2cu[3] = 0u;
    const s16x8 B2C = __builtin_bit_cast(s16x8, b2cu);

    const __hip_bfloat16* wlb = wl + lane * 8;  // lane-linear frag base

    #pragma unroll 1
    for (int t = 0; t < 2; ++t) {
        const float* spw = sp + (wid * 2 + t) * TILE_F;
        const int srow0 = wrow0 + t * 32;

        // ---- B1 fragments: window(m) = contiguous 51 floats at m*17 ----
        const float* wbase = spw + ml * NUM_POS + 8 * hi;
        u32x4 B1u[4];
        #pragma unroll
        for (int kk = 0; kk < 3; ++kk) {
            u32x4 u;
            u[0] = pkbf(wbase[kk * 16 + 0], wbase[kk * 16 + 1]);
            u[1] = pkbf(wbase[kk * 16 + 2], wbase[kk * 16 + 3]);
            u[2] = pkbf(wbase[kk * 16 + 4], wbase[kk * 16 + 5]);
            u[3] = pkbf(wbase[kk * 16 + 6], wbase[kk * 16 + 7]);
            B1u[kk] = u;
        }
        {
            float x0 = hi ? 0.0f : wbase[48];
            float x1 = hi ? 0.0f : wbase[49];
            float x2 = hi ? 0.0f : wbase[50];
            float x3 = hi ? 0.0f : 1.0f;   // k=51 bias column
            u32x4 u;
            u[0] = pkbf(x0, x1); u[1] = pkbf(x2, x3); u[2] = 0u; u[3] = 0u;
            B1u[3] = u;
        }

        // ---- GEMM1' as two hf-pairs, relu-packed immediately ----
        unsigned pk1[4][8];
        #pragma unroll
        for (int hp = 0; hp < 2; ++hp) {
            f32x16 a1a = zero16(), a1b = zero16();
            #pragma unroll
            for (int kk = 0; kk < 4; ++kk) {
                s16x8 aa = *reinterpret_cast<const s16x8*>(
                    wlb + ((2 * hp + 0) * 4 + kk) * 512);
                a1a = __builtin_amdgcn_mfma_f32_32x32x16_bf16(
                    aa, __builtin_bit_cast(s16x8, B1u[kk]), a1a, 0, 0, 0);
                s16x8 ab = *reinterpret_cast<const s16x8*>(
                    wlb + ((2 * hp + 1) * 4 + kk) * 512);
                a1b = __builtin_amdgcn_mfma_f32_32x32x16_bf16(
                    ab, __builtin_bit_cast(s16x8, B1u[kk]), a1b, 0, 0, 0);
            }
            #pragma unroll
            for (int j = 0; j < 8; ++j) {
                pk1[2 * hp + 0][j] = pkrelu(a1a[2 * j], a1a[2 * j + 1]);
                pk1[2 * hp + 1][j] = pkrelu(a1b[2 * j], a1b[2 * j + 1]);
            }
        }

        // ---- GEMM2': B-frag for step kk = pk1[kk&3][4*(kk>>2) .. +3] ----
        f32x16 acc2[2];
        acc2[0] = zero16(); acc2[1] = zero16();
        #pragma unroll
        for (int kk = 0; kk < 8; ++kk) {
            const int hf = kk & 3;
            const int jb = (kk >> 2) * 4;
            u32x4 bu;
            bu[0] = pk1[hf][jb + 0];
            bu[1] = pk1[hf][jb + 1];
            bu[2] = pk1[hf][jb + 2];
            bu[3] = pk1[hf][jb + 3];
            const s16x8 bfrag = __builtin_bit_cast(s16x8, bu);
            #pragma unroll
            for (int f = 0; f < 2; ++f) {
                s16x8 a = *reinterpret_cast<const s16x8*>(
                    wlb + (16 + kk * 2 + f) * 512);
                acc2[f] = __builtin_amdgcn_mfma_f32_32x32x16_bf16(a, bfrag, acc2[f], 0, 0, 0);
            }
        }
        #pragma unroll
        for (int f = 0; f < 2; ++f) {
            s16x8 a = *reinterpret_cast<const s16x8*>(
                wlb + (16 + 8 * 2 + f) * 512);
            acc2[f] = __builtin_amdgcn_mfma_f32_32x32x16_bf16(a, B2C, acc2[f], 0, 0, 0);
        }

        // ---- relu+pack acc2 -> pk2 ----
        unsigned pk2[2][8];
        #pragma unroll
        for (int f = 0; f < 2; ++f)
            #pragma unroll
            for (int j = 0; j < 8; ++j)
                pk2[f][j] = pkrelu(acc2[f][2 * j], acc2[f][2 * j + 1]);

        // ---- GEMM3' as two independent 2-chains ----
        f32x16 acc3a = zero16(), acc3b = zero16();
        #pragma unroll
        for (int kk = 0; kk < 4; ++kk) {
            const int f  = kk & 1;
            const int jb = (kk >> 1) * 4;
            u32x4 bu;
            bu[0] = pk2[f][jb + 0];
            bu[1] = pk2[f][jb + 1];
            bu[2] = pk2[f][jb + 2];
            bu[3] = pk2[f][jb + 3];
            const s16x8 bfrag = __builtin_bit_cast(s16x8, bu);
            s16x8 a = *reinterpret_cast<const s16x8*>(
                wlb + (34 + kk) * 512);
            if (f == 0)
                acc3a = __builtin_amdgcn_mfma_f32_32x32x16_bf16(a, bfrag, acc3a, 0, 0, 0);
            else
                acc3b = __builtin_amdgcn_mfma_f32_32x32x16_bf16(a, bfrag, acc3b, 0, 0, 0);
        }

        // ---- epilogue: sigmoid + store (hi=0 lanes hold D row 0) ----
        if (hi == 0) {
            const int grow = srow0 + ml;
            if (grow < SEQ - 2) {
                float v = acc3a[0] + acc3b[0] + b3v;
                out[(size_t)batch * (SEQ - 2) + grow] = 1.0f / (1.0f + __expf(-v));
            }
        }
    }
}

extern "C" void kernel_launch(void* const* d_in, const int* in_sizes, int n_in,
                              void* d_out, int out_size, void* d_ws, size_t ws_size,
                              hipStream_t stream) {
    const float* pos = (const float*)d_in[0];
    const float* W1  = (const float*)d_in[1];
    const float* b1  = (const float*)d_in[2];
    const float* W2  = (const float*)d_in[3];
    const float* b2  = (const float*)d_in[4];
    const float* W3  = (const float*)d_in[5];
    const float* b3  = (const float*)d_in[6];
    float* out = (float*)d_out;

    __hip_bfloat16* Wp = (__hip_bfloat16*)d_ws;  // 38 frags x 1KB = 38912 B

    prep_kernel<<<(NFRAG * 512 + 255) / 256, 256, 0, stream>>>(W1, b1, W2, b2, W3, Wp);

    // 64 batches x 32 blocks; each block = 4 waves x 2 tiles x 32 rows = 256 rows
    lpe_mfma_kernel<<<BATCH * 32, 256, 0, stream>>>(pos, Wp, b3, out);
}

// Round 8
// 34.242 us; speedup vs baseline: 1.4794x; 1.2992x over previous
//
#include <hip/hip_runtime.h>
#include <hip/hip_bf16.h>
#include <math.h>

#define NUM_POS 17
#define SEQ 8192
#define BATCH 64
#define H1 128
#define H2 64
#define NFRAG 38     // 16 (GEMM1) + 18 (GEMM2 incl bias) + 4 (GEMM3)
#define WT_U32 320   // u32 slots per window tile (306 data + 14 zero pad)

typedef __attribute__((ext_vector_type(8)))  short        s16x8;
typedef __attribute__((ext_vector_type(16))) float        f32x16;
typedef __attribute__((ext_vector_type(4)))  unsigned int u32x4;

// v_cvt_pk_bf16_f32: D[15:0]=bf16(S0), D[31:16]=bf16(S1), RNE. No builtin on gfx950.
static __device__ __forceinline__ unsigned cvtpk(float lo, float hi) {
    unsigned r;
    asm("v_cvt_pk_bf16_f32 %0, %1, %2" : "=v"(r) : "v"(lo), "v"(hi));
    return r;
}
static __device__ __forceinline__ unsigned pkrelu(float a, float b) {
    return cvtpk(fmaxf(a, 0.0f), fmaxf(b, 0.0f));
}
static __device__ __forceinline__ f32x16 zero16() {
    f32x16 z;
    #pragma unroll
    for (int i = 0; i < 16; ++i) z[i] = 0.0f;
    return z;
}

// prep: 38 MFMA A-fragments frag-packed: Wp[frag][lane][8] bf16 (1KB/frag).
//  frags 0..15 : GEMM1, id=hf*4+kk. Slot s=kk*16+hi*8+j maps to the 18-padded
//                window layout: r=s/18, f=s%18; r<3 && f<17 -> W1[(r*17+f)][h];
//                s==53 -> b1[h] (the row-2 pad slot, which the B-side stores as 1.0);
//                else 0.  (s=17,35 pad slots and s>=54 get 0 columns.)
//  frags 16..33: GEMM2, id=16+kk9*2+f. kk9<8: k-permuted W2^T; kk9==8: b2 bias col.
//  frags 34..37: GEMM3, id=34+kk. Row 0 = W3 permuted to C2' order, rows 1..31 = 0.
__global__ void prep_kernel(const float* __restrict__ W1, const float* __restrict__ b1,
                            const float* __restrict__ W2, const float* __restrict__ b2,
                            const float* __restrict__ W3,
                            __hip_bfloat16* __restrict__ Wp) {
    int idx = blockIdx.x * 256 + threadIdx.x;
    if (idx >= NFRAG * 512) return;
    int fragid = idx >> 9;
    int lane   = (idx >> 3) & 63;
    int j      = idx & 7;
    int ml = lane & 31, hi = lane >> 5;
    float v = 0.0f;
    if (fragid < 16) {
        int hf = fragid >> 2, kk = fragid & 3;
        int s = kk * 16 + hi * 8 + j;
        int h = hf * 32 + ml;
        int r = s / 18, f = s - 18 * r;
        if (r < 3) {
            if (f < 17) v = W1[(r * 17 + f) * H1 + h];
            else if (s == 53) v = b1[h];
        }
    } else if (fragid < 34) {
        int g = fragid - 16;
        int kk9 = g >> 1, f = g & 1;
        int h2 = f * 32 + ml;
        if (kk9 < 8) {
            int k = kk9 * 16 + hi * 8 + j;
            int kk = k >> 4, hb = (k >> 3) & 1, jj = k & 7;
            int hperm = (kk & 3) * 32 + 8 * (((kk >> 2) << 1) | (jj >> 2)) + (jj & 3) + 4 * hb;
            v = W2[hperm * H2 + h2];
        } else {
            v = (hi == 0 && j == 0) ? b2[h2] : 0.0f;  // k==128 bias column
        }
    } else {
        int kk = fragid - 34;
        if (ml == 0) {
            int k = kk * 16 + hi * 8 + j;
            int kk2 = k >> 4, hb = (k >> 3) & 1, jj = k & 7;
            int f = kk2 & 1;
            int r = 8 * (kk2 >> 1) + jj;
            int h2 = 32 * f + (r & 3) + 8 * (r >> 2) + 4 * hb;
            v = W3[h2];
        }
    }
    Wp[idx] = __float2bfloat16(v);
}

// main: 1024 blocks x 8 waves x 2 tiles x 32 rows. Weights in LDS (38.9KB,
// staged once per block); windows pre-packed bf16 in LDS (18-elem padded rows,
// pad slot = 1.0 for the bias trick). 2 blocks/CU -> 4 waves/SIMD.
__global__ __launch_bounds__(512, 4)
void lpe_mfma_kernel(const float* __restrict__ pos,
                     const __hip_bfloat16* __restrict__ Wp,
                     const float* __restrict__ b3,
                     float* __restrict__ out) {
    __shared__ __hip_bfloat16 wl[NFRAG * 512];   // 38912 B
    __shared__ unsigned sw[16 * WT_U32];         // 20480 B  (total 59392 B)

    const int tid  = threadIdx.x;
    const int wid  = tid >> 6;       // 0..7
    const int lane = tid & 63;
    const int ml   = lane & 31;
    const int hi   = lane >> 5;

    const int batch = blockIdx.x >> 4;   // 64 batches x 16 blocks
    const int blk   = blockIdx.x & 15;
    const int wrow0 = blk * 512 + wid * 64;

    // ---- stage weights global -> LDS (coalesced 16B copies, 512 threads) ----
    {
        const u32x4* src = reinterpret_cast<const u32x4*>(Wp);
        u32x4* dst = reinterpret_cast<u32x4*>(wl);
        #pragma unroll
        for (int it = 0; it < 5; ++it) {
            int i = it * 512 + tid;
            if (i < NFRAG * 512 * 2 / 16) dst[i] = src[i];
        }
    }

    // ---- stage 2 window tiles per wave as packed bf16, 18-elem padded rows ----
    // stored u32 p (p=0..305): R=p/9, jj=p%9; jj<8 -> (src[R*17+2jj], src[R*17+2jj+1]);
    // jj==8 -> (src[R*17+16], 1.0).  u32 306..319 zeroed.
    #pragma unroll
    for (int t = 0; t < 2; ++t) {
        unsigned* dst = sw + (wid * 2 + t) * WT_U32;
        const int srow0 = wrow0 + t * 32;
        const float* src = pos + ((size_t)batch * SEQ + srow0) * NUM_POS;
        const int lim = (SEQ - srow0) * NUM_POS;
        #pragma unroll
        for (int it = 0; it < 5; ++it) {
            int p = it * 64 + lane;
            if (p < 306) {
                int R = p / 9;
                int jj = p - 9 * R;
                int i0 = R * NUM_POS + 2 * jj;
                float a = (i0 < lim) ? src[i0] : 0.0f;
                float b;
                if (jj < 8) b = (i0 + 1 < lim) ? src[i0 + 1] : 0.0f;
                else        b = 1.0f;   // row pad slot = 1.0 (bias column carrier)
                dst[p] = cvtpk(a, b);
            }
        }
        if (lane < WT_U32 - 306) dst[306 + lane] = 0u;
    }
    __syncthreads();

    const float b3v = b3[0];

    // constant bias B-fragment for GEMM2's k=128 step
    u32x4 b2cu; b2cu[0] = (hi == 0) ? 0x3f80u : 0u; b2cu[1] = 0u; b2cu[2] = 0u; b2cu[3] = 0u;
    const s16x8 B2C = __builtin_bit_cast(s16x8, b2cu);

    const __hip_bfloat16* wlb = wl + lane * 8;  // lane-linear frag base

    #pragma unroll 1
    for (int t = 0; t < 2; ++t) {
        const int srow0 = wrow0 + t * 32;
        // lane's window = 27 consecutive u32 at ml*9 (rows m..m+2, 9 u32 each)
        const unsigned* wb = sw + (wid * 2 + t) * WT_U32 + ml * 9 + 4 * hi;

        // ---- B1 fragments: 4 x u32x4 straight from LDS, no conversions ----
        u32x4 B1u[4];
        #pragma unroll
        for (int kk = 0; kk < 4; ++kk) {
            u32x4 u;
            u[0] = wb[8 * kk + 0];
            u[1] = wb[8 * kk + 1];
            u[2] = wb[8 * kk + 2];
            u[3] = wb[8 * kk + 3];
            B1u[kk] = u;
        }

        // ---- GEMM1' as two hf-pairs, relu-packed immediately ----
        unsigned pk1[4][8];
        #pragma unroll
        for (int hp = 0; hp < 2; ++hp) {
            f32x16 a1a = zero16(), a1b = zero16();
            #pragma unroll
            for (int kk = 0; kk < 4; ++kk) {
                s16x8 aa = *reinterpret_cast<const s16x8*>(
                    wlb + ((2 * hp + 0) * 4 + kk) * 512);
                a1a = __builtin_amdgcn_mfma_f32_32x32x16_bf16(
                    aa, __builtin_bit_cast(s16x8, B1u[kk]), a1a, 0, 0, 0);
                s16x8 ab = *reinterpret_cast<const s16x8*>(
                    wlb + ((2 * hp + 1) * 4 + kk) * 512);
                a1b = __builtin_amdgcn_mfma_f32_32x32x16_bf16(
                    ab, __builtin_bit_cast(s16x8, B1u[kk]), a1b, 0, 0, 0);
            }
            #pragma unroll
            for (int j = 0; j < 8; ++j) {
                pk1[2 * hp + 0][j] = pkrelu(a1a[2 * j], a1a[2 * j + 1]);
                pk1[2 * hp + 1][j] = pkrelu(a1b[2 * j], a1b[2 * j + 1]);
            }
        }

        // ---- GEMM2': B-frag for step kk = pk1[kk&3][4*(kk>>2) .. +3] ----
        f32x16 acc2[2];
        acc2[0] = zero16(); acc2[1] = zero16();
        #pragma unroll
        for (int kk = 0; kk < 8; ++kk) {
            const int hf = kk & 3;
            const int jb = (kk >> 2) * 4;
            u32x4 bu;
            bu[0] = pk1[hf][jb + 0];
            bu[1] = pk1[hf][jb + 1];
            bu[2] = pk1[hf][jb + 2];
            bu[3] = pk1[hf][jb + 3];
            const s16x8 bfrag = __builtin_bit_cast(s16x8, bu);
            #pragma unroll
            for (int f = 0; f < 2; ++f) {
                s16x8 a = *reinterpret_cast<const s16x8*>(
                    wlb + (16 + kk * 2 + f) * 512);
                acc2[f] = __builtin_amdgcn_mfma_f32_32x32x16_bf16(a, bfrag, acc2[f], 0, 0, 0);
            }
        }
        #pragma unroll
        for (int f = 0; f < 2; ++f) {
            s16x8 a = *reinterpret_cast<const s16x8*>(
                wlb + (16 + 8 * 2 + f) * 512);
            acc2[f] = __builtin_amdgcn_mfma_f32_32x32x16_bf16(a, B2C, acc2[f], 0, 0, 0);
        }

        // ---- relu+pack acc2 -> pk2 ----
        unsigned pk2[2][8];
        #pragma unroll
        for (int f = 0; f < 2; ++f)
            #pragma unroll
            for (int j = 0; j < 8; ++j)
                pk2[f][j] = pkrelu(acc2[f][2 * j], acc2[f][2 * j + 1]);

        // ---- GEMM3' as two independent 2-chains ----
        f32x16 acc3a = zero16(), acc3b = zero16();
        #pragma unroll
        for (int kk = 0; kk < 4; ++kk) {
            const int f  = kk & 1;
            const int jb = (kk >> 1) * 4;
            u32x4 bu;
            bu[0] = pk2[f][jb + 0];
            bu[1] = pk2[f][jb + 1];
            bu[2] = pk2[f][jb + 2];
            bu[3] = pk2[f][jb + 3];
            const s16x8 bfrag = __builtin_bit_cast(s16x8, bu);
            s16x8 a = *reinterpret_cast<const s16x8*>(wlb + (34 + kk) * 512);
            if (f == 0)
                acc3a = __builtin_amdgcn_mfma_f32_32x32x16_bf16(a, bfrag, acc3a, 0, 0, 0);
            else
                acc3b = __builtin_amdgcn_mfma_f32_32x32x16_bf16(a, bfrag, acc3b, 0, 0, 0);
        }

        // ---- epilogue: sigmoid + store (hi=0 lanes hold D row 0) ----
        if (hi == 0) {
            const int grow = srow0 + ml;
            if (grow < SEQ - 2) {
                float v = acc3a[0] + acc3b[0] + b3v;
                out[(size_t)batch * (SEQ - 2) + grow] = 1.0f / (1.0f + __expf(-v));
            }
        }
    }
}

extern "C" void kernel_launch(void* const* d_in, const int* in_sizes, int n_in,
                              void* d_out, int out_size, void* d_ws, size_t ws_size,
                              hipStream_t stream) {
    const float* pos = (const float*)d_in[0];
    const float* W1  = (const float*)d_in[1];
    const float* b1  = (const float*)d_in[2];
    const float* W2  = (const float*)d_in[3];
    const float* b2  = (const float*)d_in[4];
    const float* W3  = (const float*)d_in[5];
    const float* b3  = (const float*)d_in[6];
    float* out = (float*)d_out;

    __hip_bfloat16* Wp = (__hip_bfloat16*)d_ws;  // 38 frags x 1KB = 38912 B

    prep_kernel<<<(NFRAG * 512 + 255) / 256, 256, 0, stream>>>(W1, b1, W2, b2, W3, Wp);

    // 64 batches x 16 blocks; each block = 8 waves x 2 tiles x 32 rows = 512 rows
    lpe_mfma_kernel<<<BATCH * 16, 512, 0, stream>>>(pos, Wp, b3, out);
}